// Round 3
// baseline (329.724 us; speedup 1.0000x reference)
//
#include <hip/hip_runtime.h>

#define D_MODEL 1024
#define VOCAB   50257

// One wave (64 lanes) per batch row; 4 rows per 256-thread block.
// Each lane holds 16 floats of the input row (4x float4, coalesced).
// All 16 Huffman levels are dotted into a per-lane array p[16] with 64
// independent fully-coalesced 1KB weight loads (deep memory-level
// parallelism). Then a reduce-scatter butterfly (15 shfls) reduces all 16
// dots across the 64 lanes simultaneously, leaving the full dot for level
// k=(lane>>2)&15 in each lane. Log-sigmoid runs lane-parallel for all
// levels at once; 4 shfls sum the 16 level terms. No LDS, no barriers.
__global__ __launch_bounds__(256) void hs_kernel(
    const float* __restrict__ input,       // [B, D_MODEL]
    const float* __restrict__ W,           // [VOCAB-1, D_MODEL]
    const int*   __restrict__ path_nodes,  // [VOCAB, Dmax]
    const float* __restrict__ path_signs,  // [VOCAB, Dmax]
    const int*   __restrict__ target,      // [B]
    float*       __restrict__ out,         // [B]
    int B, int Dmax)
{
    const int tid  = threadIdx.x;
    const int lane = tid & 63;
    const int wave = tid >> 6;
    const int row  = blockIdx.x * 4 + wave;
    if (row >= B) return;

    const int t = target[row];

    const float4* x4 = reinterpret_cast<const float4*>(input + (size_t)row * D_MODEL);
    const float4 x0 = x4[lane];
    const float4 x1 = x4[lane + 64];
    const float4 x2 = x4[lane + 128];
    const float4 x3 = x4[lane + 192];

    float total = 0.0f;

    for (int k0 = 0; k0 < Dmax; k0 += 16) {
        float p[16];
        #pragma unroll
        for (int j = 0; j < 16; ++j) {
            const int k = k0 + j;
            float4 w0 = make_float4(0.f, 0.f, 0.f, 0.f);
            float4 w1 = w0, w2 = w0, w3 = w0;
            if (k < Dmax) {  // wave-uniform branch
                const int node = path_nodes[t * Dmax + k];
                const float4* w4 =
                    reinterpret_cast<const float4*>(W + (size_t)node * D_MODEL);
                w0 = w4[lane];
                w1 = w4[lane + 64];
                w2 = w4[lane + 128];
                w3 = w4[lane + 192];
            }
            p[j] = x0.x * w0.x + x0.y * w0.y + x0.z * w0.z + x0.w * w0.w
                 + x1.x * w1.x + x1.y * w1.y + x1.z * w1.z + x1.w * w1.w
                 + x2.x * w2.x + x2.y * w2.y + x2.z * w2.z + x2.w * w2.w
                 + x3.x * w3.x + x3.y * w3.y + x3.z * w3.z + x3.w * w3.w;
        }

        // Reduce-scatter butterfly: 16 values x 64 lanes -> each lane ends
        // with the full 64-lane sum of value k=(lane>>2)&15.
        #pragma unroll
        for (int j = 0; j < 8; ++j) {  // xor 32: 16 -> 8 values
            const float send = (lane & 32) ? p[j] : p[j + 8];
            const float recv = __shfl_xor(send, 32);
            p[j] = ((lane & 32) ? p[j + 8] : p[j]) + recv;
        }
        #pragma unroll
        for (int j = 0; j < 4; ++j) {  // xor 16: 8 -> 4
            const float send = (lane & 16) ? p[j] : p[j + 4];
            const float recv = __shfl_xor(send, 16);
            p[j] = ((lane & 16) ? p[j + 4] : p[j]) + recv;
        }
        #pragma unroll
        for (int j = 0; j < 2; ++j) {  // xor 8: 4 -> 2
            const float send = (lane & 8) ? p[j] : p[j + 2];
            const float recv = __shfl_xor(send, 8);
            p[j] = ((lane & 8) ? p[j + 2] : p[j]) + recv;
        }
        {  // xor 4: 2 -> 1
            const float send = (lane & 4) ? p[0] : p[1];
            const float recv = __shfl_xor(send, 4);
            p[0] = ((lane & 4) ? p[1] : p[0]) + recv;
        }
        float s = p[0];
        s += __shfl_xor(s, 2);  // finish lanes-bits 1,0
        s += __shfl_xor(s, 1);
        // s = full dot for level kk = k0 + ((lane>>2)&15)

        const int kk = k0 + ((lane >> 2) & 15);
        float sgn = 0.0f;
        if (kk < Dmax) sgn = path_signs[t * Dmax + kk];
        float term = 0.0f;
        if (sgn != 0.0f) {
            const float z = sgn * s;
            term = fminf(z, 0.0f) - log1pf(expf(-fabsf(z)));
        }
        // Sum the 16 distinct level terms (bits 2..5 of lane index).
        term += __shfl_xor(term, 4);
        term += __shfl_xor(term, 8);
        term += __shfl_xor(term, 16);
        term += __shfl_xor(term, 32);
        total += term;
    }

    if (lane == 0) out[row] = total;
}

extern "C" void kernel_launch(void* const* d_in, const int* in_sizes, int n_in,
                              void* d_out, int out_size, void* d_ws, size_t ws_size,
                              hipStream_t stream) {
    const float* input      = (const float*)d_in[0];
    const float* W          = (const float*)d_in[1];
    const int*   path_nodes = (const int*)d_in[2];
    const float* path_signs = (const float*)d_in[3];
    const int*   target     = (const int*)d_in[4];
    float*       out        = (float*)d_out;

    const int B    = in_sizes[4];
    const int Dmax = in_sizes[2] / VOCAB;

    const int blocks = (B + 3) / 4;
    hs_kernel<<<blocks, 256, 0, stream>>>(input, W, path_nodes, path_signs,
                                          target, out, B, Dmax);
}

// Round 4
// 296.801 us; speedup vs baseline: 1.1109x; 1.1109x over previous
//
#include <hip/hip_runtime.h>

#define D_MODEL 1024
#define VOCAB   50257

// One block (256 threads = 4 waves) per batch row. Wave w owns levels
// 4w..4w+3 (chunked loop for generality if Dmax > 16).
// Per chunk: 16 UNCONDITIONAL float4 weight loads (clamped level index so
// padding levels load a valid row; their sign=0 kills the term) -> deep
// prefetchable MLP without the R3 full-unroll spill (max 16 float4 in
// flight, ~64 VGPR). Then 4 dots, a 6-shfl reduce-scatter leaving level
// g=(lane>>4)&3's full 64-lane dot in each lane, lane-parallel stable
// log-sigmoid, and 2 shfls to sum the 4 level terms. LDS combine of the
// 4 wave partials, single store. No atomics.
__global__ __launch_bounds__(256) void hs_kernel(
    const float* __restrict__ input,       // [B, D_MODEL]
    const float* __restrict__ W,           // [VOCAB-1, D_MODEL]
    const int*   __restrict__ path_nodes,  // [VOCAB, Dmax]
    const float* __restrict__ path_signs,  // [VOCAB, Dmax]
    const int*   __restrict__ target,      // [B]
    float*       __restrict__ out,         // [B]
    int Dmax)
{
    const int b    = blockIdx.x;
    const int tid  = threadIdx.x;
    const int lane = tid & 63;
    const int wave = tid >> 6;  // 0..3

    __shared__ int   s_nodes[64];
    __shared__ float s_signs[64];
    __shared__ float s_partial[4];

    const int t = target[b];
    for (int i = tid; i < Dmax; i += 256) {
        s_nodes[i] = path_nodes[t * Dmax + i];
        s_signs[i] = path_signs[t * Dmax + i];
    }
    __syncthreads();

    const float4* x4 = reinterpret_cast<const float4*>(input + (size_t)b * D_MODEL);
    const float4 x0 = x4[lane];
    const float4 x1 = x4[lane + 64];
    const float4 x2 = x4[lane + 128];
    const float4 x3 = x4[lane + 192];

    float acc = 0.0f;

    for (int k0 = wave * 4; k0 < Dmax; k0 += 16) {
        // Gather 4 levels' weight rows; clamp index so loads are always
        // valid (padding handled by sign==0 below).
        const float4* wp[4];
        #pragma unroll
        for (int j = 0; j < 4; ++j) {
            int k = k0 + j;
            if (k > Dmax - 1) k = Dmax - 1;
            wp[j] = reinterpret_cast<const float4*>(
                W + (size_t)s_nodes[k] * D_MODEL);
        }

        float v[4];
        #pragma unroll
        for (int j = 0; j < 4; ++j) {
            const float4 w0 = wp[j][lane];
            const float4 w1 = wp[j][lane + 64];
            const float4 w2 = wp[j][lane + 128];
            const float4 w3 = wp[j][lane + 192];
            v[j] = x0.x * w0.x + x0.y * w0.y + x0.z * w0.z + x0.w * w0.w
                 + x1.x * w1.x + x1.y * w1.y + x1.z * w1.z + x1.w * w1.w
                 + x2.x * w2.x + x2.y * w2.y + x2.z * w2.z + x2.w * w2.w
                 + x3.x * w3.x + x3.y * w3.y + x3.z * w3.z + x3.w * w3.w;
        }

        // Reduce-scatter: 4 values x 64 lanes -> 16-lane group g owns the
        // full dot of level k0+g, g = (lane>>4)&3.
        const bool b5 = (lane & 32) != 0;
        const bool b4 = (lane & 16) != 0;
        {
            const float t0 = b5 ? v[0] : v[2];
            const float t1 = b5 ? v[1] : v[3];
            const float r0 = __shfl_xor(t0, 32);
            const float r1 = __shfl_xor(t1, 32);
            const float a  = (b5 ? v[2] : v[0]) + r0;  // level 2*b5
            const float c  = (b5 ? v[3] : v[1]) + r1;  // level 2*b5+1
            const float tt = b4 ? a : c;
            const float rr = __shfl_xor(tt, 16);
            float s = (b4 ? c : a) + rr;               // level g, 4 lanes
            s += __shfl_xor(s, 8);
            s += __shfl_xor(s, 4);
            s += __shfl_xor(s, 2);
            s += __shfl_xor(s, 1);                     // full 64-lane dot

            const int kk = k0 + ((lane >> 4) & 3);
            const float sgn = (kk < Dmax) ? s_signs[kk] : 0.0f;
            float term = 0.0f;
            if (sgn != 0.0f) {
                const float z = sgn * s;
                term = fminf(z, 0.0f) - log1pf(expf(-fabsf(z)));
            }
            term += __shfl_xor(term, 16);
            term += __shfl_xor(term, 32);
            acc += term;
        }
    }

    if (lane == 0) s_partial[wave] = acc;
    __syncthreads();
    if (tid == 0)
        out[b] = s_partial[0] + s_partial[1] + s_partial[2] + s_partial[3];
}

extern "C" void kernel_launch(void* const* d_in, const int* in_sizes, int n_in,
                              void* d_out, int out_size, void* d_ws, size_t ws_size,
                              hipStream_t stream) {
    const float* input      = (const float*)d_in[0];
    const float* W          = (const float*)d_in[1];
    const int*   path_nodes = (const int*)d_in[2];
    const float* path_signs = (const float*)d_in[3];
    const int*   target     = (const int*)d_in[4];
    float*       out        = (float*)d_out;

    const int B    = in_sizes[4];
    const int Dmax = in_sizes[2] / VOCAB;

    hs_kernel<<<B, 256, 0, stream>>>(input, W, path_nodes, path_signs,
                                     target, out, Dmax);
}